// Round 3
// baseline (297.552 us; speedup 1.0000x reference)
//
#include <hip/hip_runtime.h>
#include <math.h>

#define EPSF 1e-5f

// ---------------------------------------------------------------------------
// k1: per-(b,c) plane -> row/col means -> strip pool (x + conv3 + conv7)/3 -> BN
// writes sp[b][c][0..127]  (l<64: h-strip, l>=64: w-strip)
// ---------------------------------------------------------------------------
__global__ __launch_bounds__(256) void k1_pool_strip(
    const float* __restrict__ x,
    const float* __restrict__ sph_w3, const float* __restrict__ sph_w7,
    const float* __restrict__ sph_g,  const float* __restrict__ sph_b,
    const float* __restrict__ sph_m,  const float* __restrict__ sph_v,
    const float* __restrict__ spw_w3, const float* __restrict__ spw_w7,
    const float* __restrict__ spw_g,  const float* __restrict__ spw_b,
    const float* __restrict__ spw_m,  const float* __restrict__ spw_v,
    float* __restrict__ sp)
{
    __shared__ __align__(16) float tile[64][68];   // stride 68: 16B-aligned rows
    __shared__ __align__(16) float rpart[256];     // rpart[r*4+q] row partials
    __shared__ float cpart[4][64];                 // per-wave col partials
    __shared__ float mh[64];   // row means (mean over w) -> x_h
    __shared__ float mw[64];   // col means (mean over h) -> x_w

    const int plane = blockIdx.x;          // b*256 + c
    const int c = plane & 255;
    const float* xp = x + (size_t)plane * 4096;
    const int t = threadIdx.x;
    const int r = t >> 2, q = t & 3;

    // coalesced: thread t loads bytes [64t, 64t+64) = 16 floats of row r
    const float4* src = (const float4*)(xp + r * 64 + q * 16);
    float4 v0 = src[0], v1 = src[1], v2 = src[2], v3 = src[3];
    float4* dst = (float4*)&tile[r][q * 16];
    dst[0] = v0; dst[1] = v1; dst[2] = v2; dst[3] = v3;
    // row partial sum (16 floats) computed from registers — free
    rpart[t] = (v0.x + v0.y + v0.z + v0.w) + (v1.x + v1.y + v1.z + v1.w)
             + (v2.x + v2.y + v2.z + v2.w) + (v3.x + v3.y + v3.z + v3.w);
    __syncthreads();

    // col partials: wave qw sums rows [16qw, 16qw+16) of column cc
    {
        const int cc = t & 63, qw = t >> 6;
        float s = 0.f;
        #pragma unroll
        for (int i = 0; i < 16; ++i) s += tile[qw * 16 + i][cc];  // conflict-free
        cpart[qw][cc] = s;
    }
    __syncthreads();

    if (t < 64) {
        float4 rp = ((const float4*)rpart)[t];     // ds_read_b128, conflict-free
        mh[t] = (rp.x + rp.y + rp.z + rp.w) * (1.f / 64.f);
        mw[t] = (cpart[0][t] + cpart[1][t] + cpart[2][t] + cpart[3][t]) * (1.f / 64.f);
    }
    __syncthreads();

    if (t < 128) {
        const int l = t & 63;
        const bool is_h = (t < 64);
        const float* m  = is_h ? mh     : mw;
        const float* w3 = is_h ? sph_w3 : spw_w3;
        const float* w7 = is_h ? sph_w7 : spw_w7;
        const float* g  = is_h ? sph_g  : spw_g;
        const float* bb = is_h ? sph_b  : spw_b;
        const float* mu = is_h ? sph_m  : spw_m;
        const float* vv = is_h ? sph_v  : spw_v;

        float v[7];
        #pragma unroll
        for (int j = 0; j < 7; ++j) {
            int idx = l - 3 + j;
            v[j] = (idx >= 0 && idx < 64) ? m[idx] : 0.f;
        }
        // cross-correlation (jax conv_general_dilated does not flip kernels)
        float c3 = w3[c*3+0]*v[2] + w3[c*3+1]*v[3] + w3[c*3+2]*v[4];
        float c7 = 0.f;
        #pragma unroll
        for (int j = 0; j < 7; ++j) c7 += w7[c*7+j]*v[j];

        float o = (v[3] + c3 + c7) * (1.f / 3.f);
        float scale = g[c] * rsqrtf(vv[c] + EPSF);
        o = (o - mu[c]) * scale + bb[c];
        sp[(size_t)plane * 128 + (is_h ? l : 64 + l)] = o;
    }
}

// ---------------------------------------------------------------------------
// k2: grid = (32 batches x 8 l-chunks of 16).  Per block:
//   stage sp[b][:, l0:l0+16] (16 KB) in LDS,
//   y[b][m][l0+li] = hswish(bn1(conv1_w @ sp))   -> y ws (32*8*128 floats)
// ---------------------------------------------------------------------------
__global__ __launch_bounds__(256) void k2_y(
    const float* __restrict__ sp,
    const float* __restrict__ conv1_w,
    const float* __restrict__ bn1_g, const float* __restrict__ bn1_b,
    const float* __restrict__ bn1_m, const float* __restrict__ bn1_v,
    float* __restrict__ y)
{
    __shared__ float spc[256 * 16];   // spc[c][li]
    __shared__ float w1t[256 * 8];    // conv1_w transposed: w1t[c][m]

    const int b  = blockIdx.x >> 3;
    const int lc = blockIdx.x & 7;
    const int l0 = lc * 16;
    const int t = threadIdx.x;

    const float* spb = sp + (size_t)b * 256 * 128;

    for (int j = t; j < 4096; j += 256) {
        int cc = j >> 4, li = j & 15;
        spc[j] = spb[cc * 128 + l0 + li];
    }
    for (int j = t; j < 2048; j += 256) {
        int cc = j >> 3, m = j & 7;
        w1t[j] = conv1_w[m * 256 + cc];   // tiny, L2-hot
    }
    __syncthreads();

    if (t < 128) {
        const int m = t >> 4, li = t & 15;
        float acc = 0.f;
        for (int cc = 0; cc < 256; ++cc)
            acc += w1t[cc * 8 + m] * spc[cc * 16 + li];   // broadcast reads
        float scale = bn1_g[m] * rsqrtf(bn1_v[m] + EPSF);
        float val = (acc - bn1_m[m]) * scale + bn1_b[m];
        val = val * fminf(fmaxf(val + 3.f, 0.f), 6.f) * (1.f / 6.f);  // hswish
        y[b * 1024 + m * 128 + l0 + li] = val;
    }
}

// ---------------------------------------------------------------------------
// k3: one block per (b,c) plane.  Recompute the plane's 128 attention values
// from y (L2-broadcast, ~1K MACs), overlap with the plane's x loads, then
// out = x * a_h[h] * a_w[w].
// ---------------------------------------------------------------------------
__global__ __launch_bounds__(256) void k3_apply(
    const float* __restrict__ x,
    const float* __restrict__ y,
    const float* __restrict__ convh_w, const float* __restrict__ convw_w,
    float* __restrict__ out)
{
    __shared__ __align__(16) float a_sh[128];   // [0:64] a_h, [64:128] a_w

    const int plane = blockIdx.x;          // b*256 + c
    const int b = plane >> 8, c = plane & 255;
    const int t = threadIdx.x;
    const int r = t >> 2, q = t & 3;

    // issue the plane loads first; results consumed after the barrier
    const float4* src = (const float4*)(x + (size_t)plane * 4096 + r * 64 + q * 16);
    float4 v0 = src[0], v1 = src[1], v2 = src[2], v3 = src[3];

    if (t < 128) {
        const bool is_h = (t < 64);
        const int pos = t & 63;
        const float* w  = (is_h ? convh_w : convw_w) + c * 8;
        const float* yb = y + b * 1024 + (is_h ? 0 : 64) + pos;
        float s = 0.f;
        #pragma unroll
        for (int m = 0; m < 8; ++m) s += w[m] * yb[m * 128];
        a_sh[t] = 1.f / (1.f + __expf(-s));
    }
    __syncthreads();

    const float ah = a_sh[r];
    const float4 aw0 = ((const float4*)&a_sh[64])[q * 4 + 0];
    const float4 aw1 = ((const float4*)&a_sh[64])[q * 4 + 1];
    const float4 aw2 = ((const float4*)&a_sh[64])[q * 4 + 2];
    const float4 aw3 = ((const float4*)&a_sh[64])[q * 4 + 3];

    float4* dst = (float4*)(out + (size_t)plane * 4096 + r * 64 + q * 16);
    float4 o0, o1, o2, o3;
    o0.x = v0.x * ah * aw0.x; o0.y = v0.y * ah * aw0.y;
    o0.z = v0.z * ah * aw0.z; o0.w = v0.w * ah * aw0.w;
    o1.x = v1.x * ah * aw1.x; o1.y = v1.y * ah * aw1.y;
    o1.z = v1.z * ah * aw1.z; o1.w = v1.w * ah * aw1.w;
    o2.x = v2.x * ah * aw2.x; o2.y = v2.y * ah * aw2.y;
    o2.z = v2.z * ah * aw2.z; o2.w = v2.w * ah * aw2.w;
    o3.x = v3.x * ah * aw3.x; o3.y = v3.y * ah * aw3.y;
    o3.z = v3.z * ah * aw3.z; o3.w = v3.w * ah * aw3.w;
    dst[0] = o0; dst[1] = o1; dst[2] = o2; dst[3] = o3;
}

// ---------------------------------------------------------------------------
extern "C" void kernel_launch(void* const* d_in, const int* in_sizes, int n_in,
                              void* d_out, int out_size, void* d_ws, size_t ws_size,
                              hipStream_t stream) {
    const float* x       = (const float*)d_in[0];
    const float* sph_w3  = (const float*)d_in[1];
    const float* sph_w7  = (const float*)d_in[2];
    const float* sph_g   = (const float*)d_in[3];
    const float* sph_b   = (const float*)d_in[4];
    const float* sph_m   = (const float*)d_in[5];
    const float* sph_v   = (const float*)d_in[6];
    const float* spw_w3  = (const float*)d_in[7];
    const float* spw_w7  = (const float*)d_in[8];
    const float* spw_g   = (const float*)d_in[9];
    const float* spw_b   = (const float*)d_in[10];
    const float* spw_m   = (const float*)d_in[11];
    const float* spw_v   = (const float*)d_in[12];
    const float* conv1_w = (const float*)d_in[13];
    const float* bn1_g   = (const float*)d_in[14];
    const float* bn1_b   = (const float*)d_in[15];
    const float* bn1_m   = (const float*)d_in[16];
    const float* bn1_v   = (const float*)d_in[17];
    const float* convh_w = (const float*)d_in[18];
    const float* convw_w = (const float*)d_in[19];

    float* ws  = (float*)d_ws;
    float* sp  = ws;                         // 32*256*128 = 1,048,576 floats
    float* yw  = ws + 1048576;               // 32*8*128   =    32,768 floats

    const int B = 32, C = 256;

    k1_pool_strip<<<B * C, 256, 0, stream>>>(
        x, sph_w3, sph_w7, sph_g, sph_b, sph_m, sph_v,
        spw_w3, spw_w7, spw_g, spw_b, spw_m, spw_v, sp);

    k2_y<<<B * 8, 256, 0, stream>>>(
        sp, conv1_w, bn1_g, bn1_b, bn1_m, bn1_v, yw);

    k3_apply<<<B * C, 256, 0, stream>>>(x, yw, convh_w, convw_w, (float*)d_out);
}

// Round 4
// 291.348 us; speedup vs baseline: 1.0213x; 1.0213x over previous
//
#include <hip/hip_runtime.h>
#include <math.h>

#define EPSF 1e-5f

typedef float float4v __attribute__((ext_vector_type(4)));

// ---------------------------------------------------------------------------
// k1: per-(b,c) plane -> row/col means -> strip pool (x + conv3 + conv7)/3 -> BN
// writes sp[b][c][0..127]  (l<64: h-strip, l>=64: w-strip)
// ---------------------------------------------------------------------------
__global__ __launch_bounds__(256) void k1_pool_strip(
    const float* __restrict__ x,
    const float* __restrict__ sph_w3, const float* __restrict__ sph_w7,
    const float* __restrict__ sph_g,  const float* __restrict__ sph_b,
    const float* __restrict__ sph_m,  const float* __restrict__ sph_v,
    const float* __restrict__ spw_w3, const float* __restrict__ spw_w7,
    const float* __restrict__ spw_g,  const float* __restrict__ spw_b,
    const float* __restrict__ spw_m,  const float* __restrict__ spw_v,
    float* __restrict__ sp)
{
    __shared__ __align__(16) float tile[64][68];   // stride 68: 16B-aligned rows
    __shared__ __align__(16) float rpart[256];     // rpart[r*4+q] row partials
    __shared__ float cpart[4][64];                 // per-wave col partials
    __shared__ float mh[64];   // row means (mean over w) -> x_h
    __shared__ float mw[64];   // col means (mean over h) -> x_w

    const int plane = blockIdx.x;          // b*256 + c
    const int c = plane & 255;
    const float* xp = x + (size_t)plane * 4096;
    const int t = threadIdx.x;
    const int r = t >> 2, q = t & 3;

    // coalesced: thread t loads bytes [64t, 64t+64) = 16 floats of row r
    const float4* src = (const float4*)(xp + r * 64 + q * 16);
    float4 v0 = src[0], v1 = src[1], v2 = src[2], v3 = src[3];
    float4* dst = (float4*)&tile[r][q * 16];
    dst[0] = v0; dst[1] = v1; dst[2] = v2; dst[3] = v3;
    // row partial sum (16 floats) computed from registers — free
    rpart[t] = (v0.x + v0.y + v0.z + v0.w) + (v1.x + v1.y + v1.z + v1.w)
             + (v2.x + v2.y + v2.z + v2.w) + (v3.x + v3.y + v3.z + v3.w);
    __syncthreads();

    // col partials: wave qw sums rows [16qw, 16qw+16) of column cc
    {
        const int cc = t & 63, qw = t >> 6;
        float s = 0.f;
        #pragma unroll
        for (int i = 0; i < 16; ++i) s += tile[qw * 16 + i][cc];  // conflict-free
        cpart[qw][cc] = s;
    }
    __syncthreads();

    if (t < 64) {
        float4 rp = ((const float4*)rpart)[t];     // ds_read_b128, conflict-free
        mh[t] = (rp.x + rp.y + rp.z + rp.w) * (1.f / 64.f);
        mw[t] = (cpart[0][t] + cpart[1][t] + cpart[2][t] + cpart[3][t]) * (1.f / 64.f);
    }
    __syncthreads();

    if (t < 128) {
        const int l = t & 63;
        const bool is_h = (t < 64);
        const float* m  = is_h ? mh     : mw;
        const float* w3 = is_h ? sph_w3 : spw_w3;
        const float* w7 = is_h ? sph_w7 : spw_w7;
        const float* g  = is_h ? sph_g  : spw_g;
        const float* bb = is_h ? sph_b  : spw_b;
        const float* mu = is_h ? sph_m  : spw_m;
        const float* vv = is_h ? sph_v  : spw_v;

        float v[7];
        #pragma unroll
        for (int j = 0; j < 7; ++j) {
            int idx = l - 3 + j;
            v[j] = (idx >= 0 && idx < 64) ? m[idx] : 0.f;
        }
        // cross-correlation (jax conv_general_dilated does not flip kernels)
        float c3 = w3[c*3+0]*v[2] + w3[c*3+1]*v[3] + w3[c*3+2]*v[4];
        float c7 = 0.f;
        #pragma unroll
        for (int j = 0; j < 7; ++j) c7 += w7[c*7+j]*v[j];

        float o = (v[3] + c3 + c7) * (1.f / 3.f);
        float scale = g[c] * rsqrtf(vv[c] + EPSF);
        o = (o - mu[c]) * scale + bb[c];
        sp[(size_t)plane * 128 + (is_h ? l : 64 + l)] = o;
    }
}

// ---------------------------------------------------------------------------
// k2: grid = (32 batches x 8 l-chunks of 16).  Per block:
//   stage sp[b][:, l0:l0+16] (16 KB) in LDS, y = hswish(bn1(conv1_w @ sp)),
//   then a = sigmoid(conv{h,w}_w @ y) for 256 outputs x 16 positions.
// ---------------------------------------------------------------------------
__global__ __launch_bounds__(256) void k2_mid(
    const float* __restrict__ sp,
    const float* __restrict__ conv1_w,
    const float* __restrict__ bn1_g, const float* __restrict__ bn1_b,
    const float* __restrict__ bn1_m, const float* __restrict__ bn1_v,
    const float* __restrict__ convh_w, const float* __restrict__ convw_w,
    float* __restrict__ a_h, float* __restrict__ a_w)
{
    __shared__ float spc[256 * 16];   // spc[c][li]
    __shared__ float w1t[256 * 8];    // conv1_w transposed: w1t[c][m]
    __shared__ float wos[256 * 8];    // convh_w or convw_w (o-major), per-half
    __shared__ float ys[8 * 16];      // ys[m][li]

    const int b  = blockIdx.x >> 3;
    const int lc = blockIdx.x & 7;
    const int l0 = lc * 16;
    const bool is_h = (l0 < 64);
    const int t = threadIdx.x;

    const float* spb = sp + (size_t)b * 256 * 128;
    const float* wo  = is_h ? convh_w : convw_w;

    // stage: sp slab (coalesced 64B segments), weights
    for (int j = t; j < 4096; j += 256) {
        int cc = j >> 4, li = j & 15;
        spc[j] = spb[cc * 128 + l0 + li];
    }
    for (int j = t; j < 2048; j += 256) {
        int cc = j >> 3, m = j & 7;
        w1t[j] = conv1_w[m * 256 + cc];   // transpose (L2-hot, tiny)
        wos[j] = wo[j];
    }
    __syncthreads();

    // y[m][li] = hswish(bn1(sum_c w1[m][c] * sp[c][li]))
    if (t < 128) {
        const int m = t >> 4, li = t & 15;
        float acc = 0.f;
        for (int cc = 0; cc < 256; ++cc)
            acc += w1t[cc * 8 + m] * spc[cc * 16 + li];   // broadcast reads
        float scale = bn1_g[m] * rsqrtf(bn1_v[m] + EPSF);
        float val = (acc - bn1_m[m]) * scale + bn1_b[m];
        val = val * fminf(fmaxf(val + 3.f, 0.f), 6.f) * (1.f / 6.f);  // hswish
        ys[m * 16 + li] = val;
    }
    __syncthreads();

    // a[o][l0+li] = sigmoid(sum_m wo[o][m] * y[m][li])
    float* ab = (is_h ? a_h : a_w) + (size_t)b * 256 * 64;
    const int pos0 = is_h ? l0 : l0 - 64;
    const int li = t & 15, ob = t >> 4;
    #pragma unroll
    for (int i = 0; i < 16; ++i) {
        const int o = i * 16 + ob;
        float s = 0.f;
        #pragma unroll
        for (int m = 0; m < 8; ++m)
            s += wos[o * 8 + m] * ys[m * 16 + li];
        ab[o * 64 + pos0 + li] = 1.f / (1.f + __expf(-s));
    }
}

// ---------------------------------------------------------------------------
// k3: out[b,c,h,w] = x[b,c,h,w] * a_h[b,c,h] * a_w[b,c,w]   (float4)
// Non-temporal stores: keep x L3-resident (written by k1's pass, re-read here)
// instead of letting 134 MB of out-stores evict it mid-kernel.
// ---------------------------------------------------------------------------
__global__ __launch_bounds__(256) void k3_apply(
    const float* __restrict__ x,
    const float* __restrict__ a_h, const float* __restrict__ a_w,
    float* __restrict__ out)
{
    const size_t g = (size_t)blockIdx.x * 256 + threadIdx.x;
    float4 xv = ((const float4*)x)[g];
    const size_t idx = g * 4;
    const int w0 = (int)(idx & 63);
    const int h  = (int)((idx >> 6) & 63);
    const size_t bc = idx >> 12;
    const float ah = a_h[bc * 64 + h];
    const float4 aw = *(const float4*)(a_w + bc * 64 + w0);
    float4v o;
    o.x = xv.x * ah * aw.x;
    o.y = xv.y * ah * aw.y;
    o.z = xv.z * ah * aw.z;
    o.w = xv.w * ah * aw.w;
    __builtin_nontemporal_store(o, (float4v*)out + g);
}

// ---------------------------------------------------------------------------
extern "C" void kernel_launch(void* const* d_in, const int* in_sizes, int n_in,
                              void* d_out, int out_size, void* d_ws, size_t ws_size,
                              hipStream_t stream) {
    const float* x       = (const float*)d_in[0];
    const float* sph_w3  = (const float*)d_in[1];
    const float* sph_w7  = (const float*)d_in[2];
    const float* sph_g   = (const float*)d_in[3];
    const float* sph_b   = (const float*)d_in[4];
    const float* sph_m   = (const float*)d_in[5];
    const float* sph_v   = (const float*)d_in[6];
    const float* spw_w3  = (const float*)d_in[7];
    const float* spw_w7  = (const float*)d_in[8];
    const float* spw_g   = (const float*)d_in[9];
    const float* spw_b   = (const float*)d_in[10];
    const float* spw_m   = (const float*)d_in[11];
    const float* spw_v   = (const float*)d_in[12];
    const float* conv1_w = (const float*)d_in[13];
    const float* bn1_g   = (const float*)d_in[14];
    const float* bn1_b   = (const float*)d_in[15];
    const float* bn1_m   = (const float*)d_in[16];
    const float* bn1_v   = (const float*)d_in[17];
    const float* convh_w = (const float*)d_in[18];
    const float* convw_w = (const float*)d_in[19];

    float* ws  = (float*)d_ws;
    float* sp  = ws;                         // 32*256*128 = 1,048,576 floats
    float* a_h = ws + 1048576;               // 32*256*64  =   524,288
    float* a_w = ws + 1048576 + 524288;      // 32*256*64  =   524,288

    const int B = 32, C = 256;

    k1_pool_strip<<<B * C, 256, 0, stream>>>(
        x, sph_w3, sph_w7, sph_g, sph_b, sph_m, sph_v,
        spw_w3, spw_w7, spw_g, spw_b, spw_m, spw_v, sp);

    k2_mid<<<B * 8, 256, 0, stream>>>(
        sp, conv1_w, bn1_g, bn1_b, bn1_m, bn1_v, convh_w, convw_w, a_h, a_w);

    // 32*256*64*64 / 4 floats-per-thread / 256 threads = 32768 blocks
    k3_apply<<<32768, 256, 0, stream>>>(x, a_h, a_w, (float*)d_out);
}